// Round 8
// baseline (217.992 us; speedup 1.0000x reference)
//
#include <hip/hip_runtime.h>
#include <math.h>

#define T_SEQ 2048
#define NH    32
#define NKV   8
#define HS    128
#define FD    64
#define NBLK  32          // T_SEQ / 64
#define EPSF  1e-12f
#define LDP   136         // LDS row pitch (bf16 elems)

typedef unsigned short u16;
typedef __bf16 bf16x8 __attribute__((ext_vector_type(8)));
typedef float  f32x4  __attribute__((ext_vector_type(4)));

__device__ __forceinline__ u16 f2b(float f) {
  unsigned u = __builtin_bit_cast(unsigned, f);
  return (u16)((u + 0x7fffu + ((u >> 16) & 1u)) >> 16);
}

// ws layout (bytes):
//  fqb: bf16 [NH][NBLK][64 q][128 f]      16,777,216
//  FKT: bf16 [NH][128 f][T j]             16,777,216
//  ST : bf16 [NH][NBLK][144 d][128 f]     37,748,736  (row128=z; 129..143 unused)
//  VT : bf16 [NKV][128 d][T key]           4,194,304
//  WT : bf16 [2][NH][64 f][128 d]          1,048,576
//  QB : bf16 [NH][NBLK][64 q][128 d]      16,777,216
//  KBB: bf16 [NKV][NBLK][64 k][128 d]      4,194,304
#define FQB_OFF 0
#define FKT_OFF 16777216
#define ST_OFF  33554432
#define VT_OFF  71303168
#define WT_OFF  75497472
#define QB_OFF  76546048
#define KB_OFF  93323264

// ---------------- K0: fused weight transpose + V transpose ----------------
__global__ __launch_bounds__(256) void k_pre(
    const float* __restrict__ wq, const float* __restrict__ wk,
    const float* __restrict__ vg,
    u16* __restrict__ WT, u16* __restrict__ VT)
{
  __shared__ float sB[128 * 68];
  const int bx = blockIdx.x, tid = threadIdx.x;

  if (bx < 64) {
    const int h = bx >> 1, isk = bx & 1;
    const float* src = (isk ? wk : wq) + (size_t)h * HS * FD;
    for (int idx = tid * 4; idx < 8192; idx += 1024) {
      int r = idx >> 6, c = idx & 63;
      *(float4*)(sB + r * 68 + c) = *(const float4*)(src + idx);
    }
    __syncthreads();
    u16* dst = WT + ((size_t)(isk * NH + h)) * 8192;
    for (int i = 0; i < 8; ++i) {
      int ch = tid + i * 256;
      int f = ch >> 5, d4 = (ch & 31) * 4;
      ushort4 u;
      u.x = f2b(sB[(d4 + 0) * 68 + f]);
      u.y = f2b(sB[(d4 + 1) * 68 + f]);
      u.z = f2b(sB[(d4 + 2) * 68 + f]);
      u.w = f2b(sB[(d4 + 3) * 68 + f]);
      *(ushort4*)(dst + f * 128 + d4) = u;
    }
  } else {
    const int idx2 = bx - 64;
    const int b = idx2 & 31, kvh = idx2 >> 5;
    float* sV = sB;                        // 64*129 floats
    for (int idx = tid * 4; idx < 8192; idx += 1024) {
      int r = idx >> 7, c = idx & 127;
      *(float4*)(sV + r * 129 + c) = *(const float4*)(vg + (size_t)(b * 64 + r) * (NKV * HS) + kvh * HS + c);
    }
    __syncthreads();
    const int lane = tid & 63, w = tid >> 6;
#pragma unroll
    for (int i = 0; i < 32; ++i) {
      int d = w * 32 + i;
      VT[((size_t)(kvh * 128 + d)) * T_SEQ + b * 64 + lane] = f2b(sV[lane * 129 + d]);
    }
  }
}

// ---------------- K1: feature maps (MFMA, B direct from WT) ----------------
__global__ __launch_bounds__(256) void k_fmap(
    const float* __restrict__ qg, const float* __restrict__ kg,
    const u16* __restrict__ WT,
    u16* __restrict__ fqb, u16* __restrict__ FKT,
    u16* __restrict__ QB, u16* __restrict__ KBB)
{
  __shared__ __align__(16) u16 sX[64 * 136];   // X tile; later aliased as output buf
  const int lt = blockIdx.x, h = blockIdx.y, isk = blockIdx.z;
  const int tid = threadIdx.x, lane = tid & 63, w = tid >> 6;
  const int quad = lane >> 4, txn = lane & 15;
  const int fco = quad * 8;

  const float* xbase = isk ? (kg + (h >> 2) * HS) : (qg + h * HS);
  const int    xstr  = isk ? (NKV * HS) : (NH * HS);
  for (int idx = tid * 4; idx < 8192; idx += 1024) {
    int r = idx >> 7, c = idx & 127;
    float4 v4 = *(const float4*)(xbase + (size_t)(lt * 64 + r) * xstr + c);
    ushort4 u; u.x = f2b(v4.x); u.y = f2b(v4.y); u.z = f2b(v4.z); u.w = f2b(v4.w);
    *(ushort4*)(sX + r * 136 + c) = u;
  }
  __syncthreads();

  // dump bf16 X tile for k_main (Q always; K once per kvh)
  if (!isk) {
    u16* ob = QB + ((size_t)(h * NBLK + lt)) * 8192;
    for (int i = 0; i < 4; ++i) {
      int ch = tid + i * 256;
      int row = ch >> 4, d8 = (ch & 15) * 8;
      *(uint4*)(ob + row * 128 + d8) = *(const uint4*)(sX + row * 136 + d8);
    }
  } else if ((h & 3) == 0) {
    u16* ob = KBB + ((size_t)((h >> 2) * NBLK + lt)) * 8192;
    for (int i = 0; i < 4; ++i) {
      int ch = tid + i * 256;
      int row = ch >> 4, d8 = (ch & 15) * 8;
      *(uint4*)(ob + row * 128 + d8) = *(const uint4*)(sX + row * 136 + d8);
    }
  }

  // z = X·W^T : A from LDS, B direct from WT global
  const u16* wt = WT + ((size_t)(isk * NH + h)) * 8192 + (size_t)txn * 128;
  const int arow = w * 16 + txn;
  const f32x4 vzero = {0.f, 0.f, 0.f, 0.f};
  f32x4 zt[4] = {vzero, vzero, vzero, vzero};
#pragma unroll
  for (int ks = 0; ks < 4; ++ks) {
    bf16x8 a = *(const bf16x8*)(sX + arow * 136 + ks * 32 + fco);
#pragma unroll
    for (int nt = 0; nt < 4; ++nt) {
      bf16x8 bb = *(const bf16x8*)(wt + nt * 2048 + ks * 32 + fco);
      zt[nt] = __builtin_amdgcn_mfma_f32_16x16x32_bf16(a, bb, zt[nt], 0, 0, 0);
    }
  }

  float E1[4][4], E2[4][4];
#pragma unroll
  for (int r = 0; r < 4; ++r) {
    float zv[4];
    float mx = -1e30f, mn = 1e30f;
#pragma unroll
    for (int nt = 0; nt < 4; ++nt) {
      zv[nt] = zt[nt][r];
      mx = fmaxf(mx, zv[nt]); mn = fminf(mn, zv[nt]);
    }
#pragma unroll
    for (int o = 1; o < 16; o <<= 1) {
      mx = fmaxf(mx, __shfl_xor(mx, o));
      mn = fminf(mn, __shfl_xor(mn, o));
    }
    float e1[4], e2[4], s1 = 0.f, s2 = 0.f;
#pragma unroll
    for (int nt = 0; nt < 4; ++nt) {
      e1[nt] = __expf(zv[nt] - mx); s1 += e1[nt];
      e2[nt] = __expf(mn - zv[nt]); s2 += e2[nt];
    }
#pragma unroll
    for (int o = 1; o < 16; o <<= 1) { s1 += __shfl_xor(s1, o); s2 += __shfl_xor(s2, o); }
    float r1 = 1.f / s1, r2 = 1.f / s2;
#pragma unroll
    for (int nt = 0; nt < 4; ++nt) {
      E1[r][nt] = fmaxf(e1[nt] * r1, EPSF);
      E2[r][nt] = fmaxf(e2[nt] * r2, EPSF);
    }
  }

  __syncthreads();   // all sX reads (mfma A + dumps) done before alias overwrite

  if (!isk) {
#pragma unroll
    for (int r = 0; r < 4; ++r) {
      int row = w * 16 + quad * 4 + r;
#pragma unroll
      for (int nt = 0; nt < 4; ++nt) {
        sX[row * 136 + nt * 16 + txn]      = f2b(E1[r][nt]);
        sX[row * 136 + 64 + nt * 16 + txn] = f2b(E2[r][nt]);
      }
    }
    __syncthreads();
    u16* ob = fqb + ((size_t)(h * NBLK + lt)) * 8192;
    for (int i = 0; i < 4; ++i) {
      int ch = tid + i * 256;
      int row = ch >> 4, f8 = (ch & 15) * 8;
      *(uint4*)(ob + row * 128 + f8) = *(const uint4*)(sX + row * 136 + f8);
    }
  } else {
    // FKT transposed [f][j] via LDS pitch 68 (128*68 = 8704 = 64*136, fits)
#pragma unroll
    for (int r = 0; r < 4; ++r) {
      int j = w * 16 + quad * 4 + r;
#pragma unroll
      for (int nt = 0; nt < 4; ++nt) {
        sX[(nt * 16 + txn) * 68 + j]        = f2b(E1[r][nt]);
        sX[(nt * 16 + txn + 64) * 68 + j]   = f2b(E2[r][nt]);
      }
    }
    __syncthreads();
    u16* ob = FKT + (size_t)h * 128 * T_SEQ + lt * 64;
    for (int i = 0; i < 8; ++i) {
      int ch = tid + i * 256;
      int row = ch >> 4, j4 = (ch & 15) * 4;
      *(ushort4*)(ob + (size_t)row * T_SEQ + j4) = *(const ushort4*)(sX + row * 68 + j4);
    }
  }
}

// ---------------- K2: fused state + prefix scan (direct-load, barrier-free) ----------------
// grid (8 dchunk, 2 fhalf, NH), 256 thr = 4 waves; wave w owns f n-tile w
__global__ __launch_bounds__(256) void k_scan(
    const u16* __restrict__ FKT, const u16* __restrict__ VT, u16* __restrict__ ST)
{
  const int dc = blockIdx.x, fh = blockIdx.y, h = blockIdx.z;
  const int tid = threadIdx.x, lane = tid & 63, w = tid >> 6;
  const int quad = lane >> 4, txn = lane & 15;
  const int fco = quad * 8;
  const bool doz = (dc == 0);

  bf16x8 vone;
#pragma unroll
  for (int j = 0; j < 8; ++j) vone[j] = (__bf16)1.0f;

  const u16* va = VT  + ((size_t)((h >> 2) * 128 + dc * 16 + txn)) * T_SEQ;     // A row (d)
  const u16* fb = FKT + ((size_t)(h * 128 + fh * 64 + w * 16 + txn)) * T_SEQ;   // B row (f)

  const f32x4 vzero = {0.f, 0.f, 0.f, 0.f};
  f32x4 acc = vzero, zacc = vzero;

  // register double-buffered fragments
  bf16x8 a0 = *(const bf16x8*)(va + fco);
  bf16x8 a1 = *(const bf16x8*)(va + 32 + fco);
  bf16x8 b0 = *(const bf16x8*)(fb + fco);
  bf16x8 b1 = *(const bf16x8*)(fb + 32 + fco);

  for (int b = 0; b < NBLK; ++b) {
    bf16x8 na0, na1, nb0, nb1;
    if (b + 1 < NBLK) {
      int base = (b + 1) * 64;
      na0 = *(const bf16x8*)(va + base + fco);
      na1 = *(const bf16x8*)(va + base + 32 + fco);
      nb0 = *(const bf16x8*)(fb + base + fco);
      nb1 = *(const bf16x8*)(fb + base + 32 + fco);
    }
    acc = __builtin_amdgcn_mfma_f32_16x16x32_bf16(a0, b0, acc, 0, 0, 0);
    acc = __builtin_amdgcn_mfma_f32_16x16x32_bf16(a1, b1, acc, 0, 0, 0);
    if (doz) {
      zacc = __builtin_amdgcn_mfma_f32_16x16x32_bf16(vone, b0, zacc, 0, 0, 0);
      zacc = __builtin_amdgcn_mfma_f32_16x16x32_bf16(vone, b1, zacc, 0, 0, 0);
    }
    u16* Sb = ST + (((size_t)(h * NBLK + b)) * 144 + dc * 16) * 128 + fh * 64;
#pragma unroll
    for (int r = 0; r < 4; ++r)
      Sb[(quad * 4 + r) * 128 + w * 16 + txn] = f2b(acc[r]);
    if (doz && quad == 0)
      ST[(((size_t)(h * NBLK + b)) * 144 + 128) * 128 + fh * 64 + w * 16 + txn] = f2b(zacc[0]);
    a0 = na0; a1 = na1; b0 = nb0; b1 = nb1;
  }
}

// ---------------- K4: main attention (direct-load operands, barrier-free) ----------------
// grid (NBLK, NH), 256 threads = 4 waves; wave w owns q-rows [w*16, w*16+16)
__global__ __launch_bounds__(256, 4) void k_main(
    const u16* __restrict__ QB, const u16* __restrict__ KBB,
    const u16* __restrict__ fqb, const u16* __restrict__ ST, const u16* __restrict__ VT,
    const float* __restrict__ wfac, float* __restrict__ out)
{
  __shared__ __align__(16) u16 sP[64 * LDP];   // P exchange (wave-private stripes)
  const int B = blockIdx.x, h = blockIdx.y, tid = threadIdx.x;
  const int lane = tid & 63, w = tid >> 6;
  const int quad = lane >> 4, txn = lane & 15;
  const int arow = w * 16 + txn;
  const int fco = quad * 8;

  const f32x4 vzero = {0.f, 0.f, 0.f, 0.f};
  const bf16x8 bzero = {0, 0, 0, 0, 0, 0, 0, 0};
  f32x4 y[8];
#pragma unroll
  for (int t = 0; t < 8; ++t) y[t] = vzero;
  float sln[4] = {0.f, 0.f, 0.f, 0.f};

  const int kb0 = (B >= 1) ? B - 1 : 0;

  // ---- linear part: Y += FQ · S_cum[B-2]  (+ z -> sln) ----
  if (B >= 2) {
    const u16* frow = fqb + ((size_t)(h * NBLK + B)) * 8192 + (size_t)arow * 128;
    const u16* ssrc = ST + ((size_t)(h * NBLK + (B - 2))) * 18432;
    const u16* srow = ssrc + (size_t)txn * 128;
    f32x4 yz = vzero;
#pragma unroll
    for (int ks = 0; ks < 4; ++ks) {
      bf16x8 a = *(const bf16x8*)(frow + ks * 32 + fco);
#pragma unroll
      for (int t = 0; t < 8; ++t) {
        bf16x8 bb = *(const bf16x8*)(srow + t * 2048 + ks * 32 + fco);
        y[t] = __builtin_amdgcn_mfma_f32_16x16x32_bf16(a, bb, y[t], 0, 0, 0);
      }
      bf16x8 bz = bzero;
      if (txn == 0) bz = *(const bf16x8*)(ssrc + 16384 + ks * 32 + fco);
      yz = __builtin_amdgcn_mfma_f32_16x16x32_bf16(a, bz, yz, 0, 0, 0);
    }
#pragma unroll
    for (int r = 0; r < 4; ++r) sln[r] = __shfl(yz[r], lane & 48);
  }

  // ---- scores: s[0..3] = prev block, s[4..7] = diagonal ----
  const u16* qrow = QB + ((size_t)(h * NBLK + B)) * 8192 + (size_t)arow * 128;
  const u16* kprow = KBB + ((size_t)((h >> 2) * NBLK + kb0)) * 8192 + (size_t)txn * 128;
  const u16* kdrow = KBB + ((size_t)((h >> 2) * NBLK + B)) * 8192 + (size_t)txn * 128;
  f32x4 s[8];
#pragma unroll
  for (int t = 0; t < 8; ++t) s[t] = vzero;
#pragma unroll
  for (int ks = 0; ks < 4; ++ks) {
    bf16x8 a = *(const bf16x8*)(qrow + ks * 32 + fco);
#pragma unroll
    for (int t = 0; t < 4; ++t) {
      bf16x8 bb = *(const bf16x8*)(kprow + t * 2048 + ks * 32 + fco);
      s[t] = __builtin_amdgcn_mfma_f32_16x16x32_bf16(a, bb, s[t], 0, 0, 0);
    }
#pragma unroll
    for (int t = 0; t < 4; ++t) {
      bf16x8 bb = *(const bf16x8*)(kdrow + t * 2048 + ks * 32 + fco);
      s[4 + t] = __builtin_amdgcn_mfma_f32_16x16x32_bf16(a, bb, s[4 + t], 0, 0, 0);
    }
  }

  // ---- masked softmax, write P (bf16) into sP (wave-private stripe) ----
  float wf = wfac[h];
  wf = 1.f / (1.f + __expf(-wf));
  const float scale = 0.08838834764831845f;
  float ssum[4];
#pragma unroll
  for (int r = 0; r < 4; ++r) {
    const int irow = w * 16 + quad * 4 + r;
    float sv[8];
    float m = -1e30f;
#pragma unroll
    for (int t = 0; t < 8; ++t) {
      float x = s[t][r] * scale;
      bool msk = (t < 4) ? (B == 0) : ((t - 4) * 16 + txn > irow);
      x = msk ? -1e30f : x;
      sv[t] = x;
      m = fmaxf(m, x);
    }
#pragma unroll
    for (int o = 1; o < 16; o <<= 1) m = fmaxf(m, __shfl_xor(m, o));
    float ss = 0.f;
#pragma unroll
    for (int t = 0; t < 8; ++t) {
      float e = (sv[t] > -1e29f) ? wf * __expf(sv[t] - m) : 0.f;
      ss += e;
      sP[irow * LDP + t * 16 + txn] = f2b(e);
    }
#pragma unroll
    for (int o = 1; o < 16; o <<= 1) ss += __shfl_xor(ss, o);
    ssum[r] = ss;
  }
  // no __syncthreads needed: each wave reads back only its own stripe
  // (compiler inserts lgkmcnt waits for the LDS RAW dependency)

  // ---- PV: A = P from sP, B = V^T rows direct from global ----
  const u16* vrow = VT + ((size_t)((h >> 2) * 128 + txn)) * T_SEQ;
#pragma unroll
  for (int ks = 0; ks < 4; ++ks) {
    if (B == 0 && ks < 2) continue;      // P == 0 on prev-block keys
    const int kcol = (ks < 2 ? kb0 * 64 + ks * 32 : B * 64 + (ks - 2) * 32) + fco;
    bf16x8 a = *(const bf16x8*)(sP + arow * LDP + ks * 32 + fco);
#pragma unroll
    for (int t = 0; t < 8; ++t) {
      bf16x8 bb = *(const bf16x8*)(vrow + (size_t)t * 16 * T_SEQ + kcol);
      y[t] = __builtin_amdgcn_mfma_f32_16x16x32_bf16(a, bb, y[t], 0, 0, 0);
    }
  }

  // ---- epilogue ----
  const size_t obase = ((size_t)h * T_SEQ + B * 64) * HS;
#pragma unroll
  for (int r = 0; r < 4; ++r) {
    float inv = 1.f / (ssum[r] + sln[r]);
    int irow = w * 16 + quad * 4 + r;
#pragma unroll
    for (int t = 0; t < 8; ++t)
      out[obase + (size_t)irow * HS + t * 16 + txn] = y[t][r] * inv;
  }
}

extern "C" void kernel_launch(void* const* d_in, const int* in_sizes, int n_in,
                              void* d_out, int out_size, void* d_ws, size_t ws_size,
                              hipStream_t stream) {
  const float* q    = (const float*)d_in[0];
  const float* k    = (const float*)d_in[1];
  const float* v    = (const float*)d_in[2];
  const float* wq   = (const float*)d_in[3];
  const float* wk   = (const float*)d_in[4];
  const float* wfac = (const float*)d_in[5];
  float* out = (float*)d_out;
  char* wsb = (char*)d_ws;

  u16* fqb = (u16*)(wsb + FQB_OFF);
  u16* FKT = (u16*)(wsb + FKT_OFF);
  u16* ST  = (u16*)(wsb + ST_OFF);
  u16* VT  = (u16*)(wsb + VT_OFF);
  u16* WT  = (u16*)(wsb + WT_OFF);
  u16* QB  = (u16*)(wsb + QB_OFF);
  u16* KBB = (u16*)(wsb + KB_OFF);

  k_pre  <<<dim3(320),         256, 0, stream>>>(wq, wk, v, WT, VT);
  k_fmap <<<dim3(NBLK, NH, 2), 256, 0, stream>>>(q, k, WT, fqb, FKT, QB, KBB);
  k_scan <<<dim3(8, 2, NH),    256, 0, stream>>>(FKT, VT, ST);
  k_main <<<dim3(NBLK, NH),    256, 0, stream>>>(QB, KBB, fqb, ST, VT, wfac, out);
}